// Round 3
// baseline (98.988 us; speedup 1.0000x reference)
//
#include <hip/hip_runtime.h>
#include <hip/hip_bf16.h>

// ContrastiveLoss: N=8192, D=256, NUM_IDS=1000, MARGIN=0.3
// sim = X X^T (bf16 MFMA), fused mask+loss epilogue, upper-triangle only.
// R3: 256x256 tile, 8 waves (2x4), per-wave 128x64 (42.7 FLOP/LDS-byte),
//     double-buffered BK=64 prefetch, rare-branch epilogue.

#define NROWS 8192
#define DDIM  256
#define MARGINF 0.3f

typedef __attribute__((ext_vector_type(8))) short short8x;   // 8 bf16 (4 VGPRs)
typedef __attribute__((ext_vector_type(4))) float f32x4;     // 4 fp32 acc

// ---------- round-to-nearest-even f32 -> bf16 bits ----------
__device__ __forceinline__ unsigned short f2bf(float f) {
    unsigned int u = __float_as_uint(f);
    unsigned int r = (u + 0x7fffu + ((u >> 16) & 1u)) >> 16;
    return (unsigned short)r;
}

// ---------- pass 1: fp32 -> bf16 convert (2M elems, 8/thread) ----------
__global__ void __launch_bounds__(256) convert_k(const float* __restrict__ x,
                                                 unsigned short* __restrict__ xb) {
    int i = blockIdx.x * 256 + threadIdx.x;          // 0 .. 262143
    const float4* p = reinterpret_cast<const float4*>(x) + (size_t)i * 2;
    float4 a = p[0];
    float4 b = p[1];
    short8x o;
    o[0] = (short)f2bf(a.x); o[1] = (short)f2bf(a.y);
    o[2] = (short)f2bf(a.z); o[3] = (short)f2bf(a.w);
    o[4] = (short)f2bf(b.x); o[5] = (short)f2bf(b.y);
    o[6] = (short)f2bf(b.z); o[7] = (short)f2bf(b.w);
    reinterpret_cast<short8x*>(xb)[i] = o;
}

// ---------- pass 2: fused GEMM + contrastive-loss epilogue ----------
// 256x256 tile per block, 8 waves (2Mx4N), per-wave 128x64 via 8x4 of 16x16x32.
// BK=64 double-buffered: LDS 2 x ([256][64] A + [256][64] B) = 128KB.
// XOR swizzle chunk^=(row&7): linear LDS dest, pre-swizzled global source,
// same XOR on ds_read (rule #21). Verified 2-way-max banking in R1/R2 (0 conflicts).
__global__ void __launch_bounds__(512, 2) gemm_loss_k(const unsigned short* __restrict__ xb,
                                                      const int* __restrict__ tg,
                                                      double* __restrict__ partials) {
    // ---- 1D upper-triangle decode over 32x32 tile grid: p -> (bi <= bj) ----
    const int p = blockIdx.x;
    int bi = (int)(32.5f - sqrtf(32.5f * 32.5f - 2.0f * (float)p));
    if (bi < 0) bi = 0;
    if (bi > 31) bi = 31;
    while (bi > 0 && (bi * (65 - bi)) / 2 > p) --bi;
    while (((bi + 1) * (64 - bi)) / 2 <= p) ++bi;
    const int bj = bi + (p - (bi * (65 - bi)) / 2);

    __shared__ unsigned short lA[2][256 * 64];   // 2 x 32 KB
    __shared__ unsigned short lB[2][256 * 64];   // 2 x 32 KB
    __shared__ int lti[256];
    __shared__ int ltj[256];
    __shared__ float redbuf[8];

    const int tid  = threadIdx.x;
    const int lane = tid & 63;
    const int wid  = tid >> 6;       // 0..7
    const int wr   = wid >> 2;       // wave row (0..1) -> 128 rows
    const int wc   = wid & 3;        // wave col (0..3) -> 64 cols

    if (tid < 256)       lti[tid]        = tg[bi * 256 + tid];
    else                 ltj[tid - 256]  = tg[bj * 256 + (tid - 256)];

    // ---- staging addressing (pre-swizzled source, linear LDS dest) ----
    // issue = 1KB = 8 rows of 128B. LDS[r][c] holds global[r][c ^ (r&7)].
    const int lrow   = lane >> 3;
    const int schunk = ((lane & 7) ^ lrow) << 4;

    const char* aBase = (const char*)(xb + (size_t)bi * 256 * 256);
    const char* bBase = (const char*)(xb + (size_t)bj * 256 * 256);

    // ---- ds_read fragment addressing (16x16x32: row=lane&15, k=(lane>>4)*8+j) ----
    const int g  = lane >> 4;        // 0..3
    const int x7 = lane & 7;
    int koff[2], arow[8], brow[4];
#pragma unroll
    for (int kk = 0; kk < 2; ++kk) koff[kk] = (((kk * 4 + g) ^ x7) << 3);
#pragma unroll
    for (int m = 0; m < 8; ++m) arow[m] = (wr * 128 + m * 16 + (lane & 15)) * 64;
#pragma unroll
    for (int n = 0; n < 4; ++n) brow[n] = (wc * 64 + n * 16 + (lane & 15)) * 64;

    f32x4 acc[8][4] = {};

    // stage one BK=64 slab (A+B) into buffer `buf`
    auto STAGE = [&](int buf, int ks) {
        const int k0b = ks * 128;     // K-slab byte offset within a 512B row
#pragma unroll
        for (int t = 0; t < 4; ++t) {
            const int issue = wid * 4 + t;              // 0..31 (wave-uniform)
            const int r = issue * 8 + lrow;             // tile row 0..255
            const char* sa = aBase + (size_t)r * 512 + k0b + schunk;
            const char* sb = bBase + (size_t)r * 512 + k0b + schunk;
            __builtin_amdgcn_global_load_lds(
                (const __attribute__((address_space(1))) unsigned int*)sa,
                (__attribute__((address_space(3))) unsigned int*)&lA[buf][issue * 512],
                16, 0, 0);
            __builtin_amdgcn_global_load_lds(
                (const __attribute__((address_space(1))) unsigned int*)sb,
                (__attribute__((address_space(3))) unsigned int*)&lB[buf][issue * 512],
                16, 0, 0);
        }
    };

    STAGE(0, 0);
    __syncthreads();                 // buf0 ready

    int buf = 0;
#pragma unroll
    for (int ks = 0; ks < 4; ++ks) {
        if (ks < 3) STAGE(buf ^ 1, ks + 1);   // prefetch next slab under compute

        const unsigned short* la = lA[buf];
        const unsigned short* lb = lB[buf];
#pragma unroll
        for (int kk = 0; kk < 2; ++kk) {
            short8x af[8], bf[4];
#pragma unroll
            for (int m = 0; m < 8; ++m)
                af[m] = *(const short8x*)&la[arow[m] + koff[kk]];
#pragma unroll
            for (int n = 0; n < 4; ++n)
                bf[n] = *(const short8x*)&lb[brow[n] + koff[kk]];
            __builtin_amdgcn_s_setprio(1);
#pragma unroll
            for (int m = 0; m < 8; ++m)
#pragma unroll
                for (int n = 0; n < 4; ++n)
                    acc[m][n] = __builtin_amdgcn_mfma_f32_16x16x32_bf16(
                        af[m], bf[n], acc[m][n], 0, 0, 0);
            __builtin_amdgcn_s_setprio(0);
        }

        if (ks < 3) { __syncthreads(); buf ^= 1; }  // drain prefetch, swap
    }

    // ---- epilogue: masks + loss ----
    // C/D layout (m89): col = lane&15, row = (lane>>4)*4 + reg
    const int colbase = wc * 64 + (lane & 15);
    int tjv[4];
#pragma unroll
    for (int n = 0; n < 4; ++n) tjv[n] = ltj[colbase + n * 16];

    float lsum = 0.f;
    if (bi != bj) {
        // off-diagonal: cheap neg path + rarely-taken same-label correction
#pragma unroll
        for (int m = 0; m < 8; ++m) {
#pragma unroll
            for (int r = 0; r < 4; ++r) {
                const int ti = lti[wr * 128 + m * 16 + (g << 2) + r];
#pragma unroll
                for (int n = 0; n < 4; ++n) {
                    const float s = acc[m][n][r];
                    const float negv = (s > MARGINF) ? s : 0.0f;
                    lsum += negv;
                    if (__builtin_expect(ti == tjv[n], 0))
                        lsum += fmaxf(1.0f - s, 0.0f) - negv;
                }
            }
        }
        lsum *= 2.0f;
    } else {
        // diagonal tile: strict-upper x2, diagonal x1, lower x0
#pragma unroll
        for (int m = 0; m < 8; ++m) {
#pragma unroll
            for (int r = 0; r < 4; ++r) {
                const int rl = wr * 128 + m * 16 + (g << 2) + r;
                const int ti = lti[rl];
#pragma unroll
                for (int n = 0; n < 4; ++n) {
                    const int cl = colbase + n * 16;
                    const float s = acc[m][n][r];
                    const float posv = fmaxf(1.0f - s, 0.0f);
                    const float negv = (s > MARGINF) ? s : 0.0f;
                    const float c = (ti == tjv[n]) ? posv : negv;
                    const float w = (cl > rl) ? 2.0f : ((cl == rl) ? 1.0f : 0.0f);
                    lsum += w * c;
                }
            }
        }
    }

    // wave reduce then cross-wave
#pragma unroll
    for (int mask = 1; mask < 64; mask <<= 1) lsum += __shfl_xor(lsum, mask, 64);
    if (lane == 0) redbuf[wid] = lsum;
    __syncthreads();
    if (tid == 0) {
        float t = 0.f;
#pragma unroll
        for (int w = 0; w < 8; ++w) t += redbuf[w];
        partials[p] = (double)t;
    }
}

// ---------- pass 3: sum partials, divide by N ----------
__global__ void __launch_bounds__(256) finalize_k(const double* __restrict__ partials,
                                                  float* __restrict__ out) {
    double s = 0.0;
    for (int i = threadIdx.x; i < 528; i += 256) s += partials[i];
#pragma unroll
    for (int mask = 1; mask < 64; mask <<= 1) s += __shfl_xor(s, mask, 64);
    __shared__ double red[4];
    const int wid = threadIdx.x >> 6;
    if ((threadIdx.x & 63) == 0) red[wid] = s;
    __syncthreads();
    if (threadIdx.x == 0)
        out[0] = (float)((red[0] + red[1] + red[2] + red[3]) / 8192.0);
}

extern "C" void kernel_launch(void* const* d_in, const int* in_sizes, int n_in,
                              void* d_out, int out_size, void* d_ws, size_t ws_size,
                              hipStream_t stream) {
    (void)in_sizes; (void)n_in; (void)out_size; (void)ws_size;
    const float* x  = (const float*)d_in[0];
    const int*   tg = (const int*)d_in[1];
    float* out = (float*)d_out;

    double* partials   = (double*)d_ws;                          // 528 * 8B
    unsigned short* xb = (unsigned short*)((char*)d_ws + 32768); // 4MB bf16 X

    convert_k<<<1024, 256, 0, stream>>>(x, xb);
    gemm_loss_k<<<528, 512, 0, stream>>>(xb, tg, partials);
    finalize_k<<<1, 256, 0, stream>>>(partials, out);
}

// Round 4
// 92.247 us; speedup vs baseline: 1.0731x; 1.0731x over previous
//
#include <hip/hip_runtime.h>
#include <hip/hip_bf16.h>

// ContrastiveLoss: N=8192, D=256, NUM_IDS=1000, MARGIN=0.3
// R4: LDS-free GEMM. X is pre-converted to a fragment-major bf16 layout so
// every 16x16x32 MFMA fragment is one contiguous 1KB global load (L2-resident).
// No __syncthreads in the K-loop, no staging barriers, no races.

#define MARGINF 0.3f

typedef __attribute__((ext_vector_type(8))) short short8x;   // 8 bf16 (4 VGPRs)
typedef __attribute__((ext_vector_type(4))) float f32x4;     // 4 fp32 acc

// ---------- round-to-nearest-even f32 -> bf16 bits ----------
__device__ __forceinline__ unsigned short f2bf(float f) {
    unsigned int u = __float_as_uint(f);
    unsigned int r = (u + 0x7fffu + ((u >> 16) & 1u)) >> 16;
    return (unsigned short)r;
}

// ---------- pass 1: fp32 -> bf16 fragment-major convert ----------
// Output unit u (16B): lane = u&63, kk = (u>>6)&7, r16 = u>>9.
// Holds X[r16*16 + (lane&15)][kk*32 + (lane>>4)*8 .. +8] as 8 bf16.
// => fragment (r16, kk) is contiguous: elem idx = (r16*8+kk)*64 + lane.
__global__ void __launch_bounds__(256) convert_k(const float* __restrict__ x,
                                                 unsigned short* __restrict__ xb) {
    int u = blockIdx.x * 256 + threadIdx.x;          // 0 .. 262143
    int lane = u & 63;
    int kk   = (u >> 6) & 7;
    int r16  = u >> 9;
    int row  = r16 * 16 + (lane & 15);
    int col  = kk * 32 + (lane >> 4) * 8;
    const float4* src = reinterpret_cast<const float4*>(x + (size_t)row * 256 + col);
    float4 a = src[0];
    float4 b = src[1];
    short8x o;
    o[0] = (short)f2bf(a.x); o[1] = (short)f2bf(a.y);
    o[2] = (short)f2bf(a.z); o[3] = (short)f2bf(a.w);
    o[4] = (short)f2bf(b.x); o[5] = (short)f2bf(b.y);
    o[6] = (short)f2bf(b.z); o[7] = (short)f2bf(b.w);
    reinterpret_cast<short8x*>(xb)[u] = o;
}

// ---------- pass 2: LDS-free fused GEMM + contrastive-loss epilogue ----------
// 128x128 tile per block, 4 waves (2x2), each wave 64x64 via 4x4 of 16x16x32.
// Fragments loaded directly from fragment-major global (L2-resident, 1KB
// contiguous per load). K-loop has zero barriers.
__global__ void __launch_bounds__(256, 3) gemm_loss_k(const unsigned short* __restrict__ xb,
                                                      const int* __restrict__ tg,
                                                      double* __restrict__ partials) {
    // ---- 1D upper-triangle decode: p -> (bi <= bj), 64x64 tile grid ----
    const int p = blockIdx.x;
    int bi = (int)(64.5f - sqrtf(64.5f * 64.5f - 2.0f * (float)p));
    if (bi < 0) bi = 0;
    if (bi > 63) bi = 63;
    while (bi > 0 && (bi * (129 - bi)) / 2 > p) --bi;
    while (((bi + 1) * (128 - bi)) / 2 <= p) ++bi;
    const int bj = bi + (p - (bi * (129 - bi)) / 2);

    __shared__ int lti[128];
    __shared__ int ltj[128];
    __shared__ float redbuf[4];

    const int tid  = threadIdx.x;
    const int lane = tid & 63;
    const int wid  = tid >> 6;       // 0..3
    const int wr   = wid >> 1;       // wave row (0..1)
    const int wc   = wid & 1;        // wave col (0..1)

    if (tid < 128)       lti[tid]        = tg[bi * 128 + tid];
    else                 ltj[tid - 128]  = tg[bj * 128 + (tid - 128)];
    __syncthreads();

    const short8x* xf = reinterpret_cast<const short8x*>(xb);
    // fragment element index: (r16*8 + kk)*64 + lane
    const int aIdx = (bi * 8 + wr * 4) * 512 + lane;   // + m*512 + kk*64
    const int bIdx = (bj * 8 + wc * 4) * 512 + lane;   // + n*512 + kk*64

    f32x4 acc[4][4] = {};

#pragma unroll
    for (int kk = 0; kk < 8; ++kk) {
        short8x af[4], bf[4];
#pragma unroll
        for (int n = 0; n < 4; ++n) bf[n] = xf[bIdx + n * 512 + kk * 64];
#pragma unroll
        for (int m = 0; m < 4; ++m) af[m] = xf[aIdx + m * 512 + kk * 64];
#pragma unroll
        for (int m = 0; m < 4; ++m)
#pragma unroll
            for (int n = 0; n < 4; ++n)
                acc[m][n] = __builtin_amdgcn_mfma_f32_16x16x32_bf16(
                    af[m], bf[n], acc[m][n], 0, 0, 0);
    }

    // ---- epilogue: masks + loss (verified R2 path) ----
    // C/D layout (m89): col = lane&15, row = (lane>>4)*4 + reg
    const int g = lane >> 4;
    const int colbase = wc * 64 + (lane & 15);
    int tjv[4];
#pragma unroll
    for (int n = 0; n < 4; ++n) tjv[n] = ltj[colbase + n * 16];

    float lsum = 0.f;
    if (bi != bj) {
        // off-diagonal tile: every element counts twice (symmetry)
#pragma unroll
        for (int m = 0; m < 4; ++m) {
#pragma unroll
            for (int r = 0; r < 4; ++r) {
                const int ti = lti[wr * 64 + m * 16 + (g << 2) + r];
#pragma unroll
                for (int n = 0; n < 4; ++n) {
                    const float s = acc[m][n][r];
                    const float posv = fmaxf(1.0f - s, 0.0f);
                    const float negv = (s > MARGINF) ? s : 0.0f;
                    lsum += (ti == tjv[n]) ? posv : negv;
                }
            }
        }
        lsum *= 2.0f;
    } else {
        // diagonal tile: strict-upper x2, diagonal x1, lower x0
#pragma unroll
        for (int m = 0; m < 4; ++m) {
#pragma unroll
            for (int r = 0; r < 4; ++r) {
                const int rl = wr * 64 + m * 16 + (g << 2) + r;
                const int ti = lti[rl];
#pragma unroll
                for (int n = 0; n < 4; ++n) {
                    const int cl = colbase + n * 16;
                    const float s = acc[m][n][r];
                    const float posv = fmaxf(1.0f - s, 0.0f);
                    const float negv = (s > MARGINF) ? s : 0.0f;
                    const float c = (ti == tjv[n]) ? posv : negv;
                    const float w = (cl > rl) ? 2.0f : ((cl == rl) ? 1.0f : 0.0f);
                    lsum += w * c;
                }
            }
        }
    }

    // wave reduce then cross-wave
#pragma unroll
    for (int mask = 1; mask < 64; mask <<= 1) lsum += __shfl_xor(lsum, mask, 64);
    if (lane == 0) redbuf[wid] = lsum;
    __syncthreads();
    if (tid == 0)
        partials[p] = (double)(redbuf[0] + redbuf[1] + redbuf[2] + redbuf[3]);
}

// ---------- pass 3: sum partials, divide by N ----------
__global__ void __launch_bounds__(256) finalize_k(const double* __restrict__ partials,
                                                  float* __restrict__ out) {
    double s = 0.0;
    for (int i = threadIdx.x; i < 2080; i += 256) s += partials[i];
#pragma unroll
    for (int mask = 1; mask < 64; mask <<= 1) s += __shfl_xor(s, mask, 64);
    __shared__ double red[4];
    const int wid = threadIdx.x >> 6;
    if ((threadIdx.x & 63) == 0) red[wid] = s;
    __syncthreads();
    if (threadIdx.x == 0)
        out[0] = (float)((red[0] + red[1] + red[2] + red[3]) / 8192.0);
}

extern "C" void kernel_launch(void* const* d_in, const int* in_sizes, int n_in,
                              void* d_out, int out_size, void* d_ws, size_t ws_size,
                              hipStream_t stream) {
    (void)in_sizes; (void)n_in; (void)out_size; (void)ws_size;
    const float* x  = (const float*)d_in[0];
    const int*   tg = (const int*)d_in[1];
    float* out = (float*)d_out;

    double* partials   = (double*)d_ws;                          // 2080 * 8B
    unsigned short* xb = (unsigned short*)((char*)d_ws + 32768); // 4MB bf16 X (frag-major)

    convert_k<<<1024, 256, 0, stream>>>(x, xb);
    gemm_loss_k<<<2080, 256, 0, stream>>>(xb, tg, partials);
    finalize_k<<<1, 256, 0, stream>>>(partials, out);
}

// Round 5
// 89.259 us; speedup vs baseline: 1.1090x; 1.0335x over previous
//
#include <hip/hip_runtime.h>
#include <hip/hip_bf16.h>

// ContrastiveLoss: N=8192, D=256, NUM_IDS=1000, MARGIN=0.3
// R5: LDS-free GEMM with 32x32x16 MFMA. X pre-converted to 32x32 fragment-major
// bf16 blobs (1KB contiguous per fragment load, L2-resident). Explicit 2-stage
// register pipeline in the K-loop; zero barriers in the K-loop.

#define MARGINF 0.3f

typedef __attribute__((ext_vector_type(8))) short short8x;    // 8 bf16 (4 VGPRs)
typedef __attribute__((ext_vector_type(16))) float f32x16;    // 16 fp32 acc

// ---------- round-to-nearest-even f32 -> bf16 bits ----------
__device__ __forceinline__ unsigned short f2bf(float f) {
    unsigned int u = __float_as_uint(f);
    unsigned int r = (u + 0x7fffu + ((u >> 16) & 1u)) >> 16;
    return (unsigned short)r;
}

// ---------- pass 1: fp32 -> bf16 fragment-major convert (32x32 frags) ----------
// Unit u (16B): lane = u&63, ks = (u>>6)&15, r32 = u>>10.
// Holds X[r32*32 + (lane&31)][ks*16 + (lane>>5)*8 .. +8] as 8 bf16.
// => fragment (r32, ks) contiguous: short8x index = (r32*16 + ks)*64 + lane.
__global__ void __launch_bounds__(256) convert_k(const float* __restrict__ x,
                                                 unsigned short* __restrict__ xb) {
    int u = blockIdx.x * 256 + threadIdx.x;          // 0 .. 262143
    int lane = u & 63;
    int ks   = (u >> 6) & 15;
    int r32  = u >> 10;
    int row  = r32 * 32 + (lane & 31);
    int col  = ks * 16 + (lane >> 5) * 8;
    const float4* src = reinterpret_cast<const float4*>(x + (size_t)row * 256 + col);
    float4 a = src[0];
    float4 b = src[1];
    short8x o;
    o[0] = (short)f2bf(a.x); o[1] = (short)f2bf(a.y);
    o[2] = (short)f2bf(a.z); o[3] = (short)f2bf(a.w);
    o[4] = (short)f2bf(b.x); o[5] = (short)f2bf(b.y);
    o[6] = (short)f2bf(b.z); o[7] = (short)f2bf(b.w);
    reinterpret_cast<short8x*>(xb)[u] = o;
}

// ---------- pass 2: LDS-free fused GEMM + loss, 32x32x16 MFMA ----------
// 128x128 tile per block, 4 waves (2x2), each wave 64x64 via 2x2 of 32x32x16.
// 16 k-steps of K=16; explicit 2-stage register pipeline (loads 1 step ahead).
__global__ void __launch_bounds__(256, 3) gemm_loss_k(const unsigned short* __restrict__ xb,
                                                      const int* __restrict__ tg,
                                                      double* __restrict__ partials) {
    // ---- 1D upper-triangle decode: p -> (bi <= bj), 64x64 tile grid ----
    const int p = blockIdx.x;
    int bi = (int)(64.5f - sqrtf(64.5f * 64.5f - 2.0f * (float)p));
    if (bi < 0) bi = 0;
    if (bi > 63) bi = 63;
    while (bi > 0 && (bi * (129 - bi)) / 2 > p) --bi;
    while (((bi + 1) * (128 - bi)) / 2 <= p) ++bi;
    const int bj = bi + (p - (bi * (129 - bi)) / 2);

    __shared__ int lti[128];
    __shared__ int ltj[128];
    __shared__ float redbuf[4];

    const int tid  = threadIdx.x;
    const int lane = tid & 63;
    const int wid  = tid >> 6;       // 0..3
    const int wr   = wid >> 1;       // wave row (0..1)
    const int wc   = wid & 1;        // wave col (0..1)

    if (tid < 128)       lti[tid]        = tg[bi * 128 + tid];
    else                 ltj[tid - 128]  = tg[bj * 128 + (tid - 128)];
    __syncthreads();

    const short8x* xf = reinterpret_cast<const short8x*>(xb);
    // fragment short8x index: (r32*16 + ks)*64 + lane ; fm/fn step r32 by 1 (+1024)
    const int aIdx = ((bi * 4 + wr * 2) << 10) + lane;   // + fm*1024 + ks*64
    const int bIdx = ((bj * 4 + wc * 2) << 10) + lane;   // + fn*1024 + ks*64

    f32x16 acc00 = {}, acc01 = {}, acc10 = {}, acc11 = {};

    short8x a0 = xf[aIdx];
    short8x a1 = xf[aIdx + 1024];
    short8x b0 = xf[bIdx];
    short8x b1 = xf[bIdx + 1024];

#pragma unroll
    for (int ks = 0; ks < 16; ++ks) {
        short8x na0, na1, nb0, nb1;
        if (ks < 15) {
            const int o = (ks + 1) * 64;
            na0 = xf[aIdx + o];
            na1 = xf[aIdx + 1024 + o];
            nb0 = xf[bIdx + o];
            nb1 = xf[bIdx + 1024 + o];
        }
        acc00 = __builtin_amdgcn_mfma_f32_32x32x16_bf16(a0, b0, acc00, 0, 0, 0);
        acc01 = __builtin_amdgcn_mfma_f32_32x32x16_bf16(a0, b1, acc01, 0, 0, 0);
        acc10 = __builtin_amdgcn_mfma_f32_32x32x16_bf16(a1, b0, acc10, 0, 0, 0);
        acc11 = __builtin_amdgcn_mfma_f32_32x32x16_bf16(a1, b1, acc11, 0, 0, 0);
        if (ks < 15) { a0 = na0; a1 = na1; b0 = nb0; b1 = nb1; }
    }

    // ---- epilogue: masks + loss ----
    // 32x32 C/D layout (m74/m101): col = lane&31, row = (reg&3)+8*(reg>>2)+4*(lane>>5)
    const int hi4 = (lane >> 5) * 4;
    const int col_l = lane & 31;
    int tjv[2];
#pragma unroll
    for (int fn = 0; fn < 2; ++fn) tjv[fn] = ltj[wc * 64 + fn * 32 + col_l];

    float lsum = 0.f;
    const f32x16* accs[4] = { &acc00, &acc01, &acc10, &acc11 };

    if (bi != bj) {
        // off-diagonal tile: every element counts twice (symmetry)
#pragma unroll
        for (int fm = 0; fm < 2; ++fm) {
#pragma unroll
            for (int fn = 0; fn < 2; ++fn) {
                const f32x16& A = *accs[fm * 2 + fn];
                const int tj = tjv[fn];
#pragma unroll
                for (int r = 0; r < 16; ++r) {
                    const int row_l = (r & 3) + 8 * (r >> 2) + hi4;
                    const int ti = lti[wr * 64 + fm * 32 + row_l];
                    const float s = A[r];
                    const float posv = fmaxf(1.0f - s, 0.0f);
                    const float negv = (s > MARGINF) ? s : 0.0f;
                    lsum += (ti == tj) ? posv : negv;
                }
            }
        }
        lsum *= 2.0f;
    } else {
        // diagonal tile: strict-upper x2, diagonal x1, lower x0
#pragma unroll
        for (int fm = 0; fm < 2; ++fm) {
#pragma unroll
            for (int fn = 0; fn < 2; ++fn) {
                const f32x16& A = *accs[fm * 2 + fn];
                const int tj = tjv[fn];
                const int cl = wc * 64 + fn * 32 + col_l;
#pragma unroll
                for (int r = 0; r < 16; ++r) {
                    const int row_l = (r & 3) + 8 * (r >> 2) + hi4;
                    const int rl = wr * 64 + fm * 32 + row_l;
                    const int ti = lti[rl];
                    const float s = A[r];
                    const float posv = fmaxf(1.0f - s, 0.0f);
                    const float negv = (s > MARGINF) ? s : 0.0f;
                    const float c = (ti == tj) ? posv : negv;
                    const float w = (cl > rl) ? 2.0f : ((cl == rl) ? 1.0f : 0.0f);
                    lsum += w * c;
                }
            }
        }
    }

    // wave reduce then cross-wave
#pragma unroll
    for (int mask = 1; mask < 64; mask <<= 1) lsum += __shfl_xor(lsum, mask, 64);
    if (lane == 0) redbuf[wid] = lsum;
    __syncthreads();
    if (tid == 0)
        partials[p] = (double)(redbuf[0] + redbuf[1] + redbuf[2] + redbuf[3]);
}

// ---------- pass 3: sum partials, divide by N ----------
__global__ void __launch_bounds__(256) finalize_k(const double* __restrict__ partials,
                                                  float* __restrict__ out) {
    double s = 0.0;
    for (int i = threadIdx.x; i < 2080; i += 256) s += partials[i];
#pragma unroll
    for (int mask = 1; mask < 64; mask <<= 1) s += __shfl_xor(s, mask, 64);
    __shared__ double red[4];
    const int wid = threadIdx.x >> 6;
    if ((threadIdx.x & 63) == 0) red[wid] = s;
    __syncthreads();
    if (threadIdx.x == 0)
        out[0] = (float)((red[0] + red[1] + red[2] + red[3]) / 8192.0);
}

extern "C" void kernel_launch(void* const* d_in, const int* in_sizes, int n_in,
                              void* d_out, int out_size, void* d_ws, size_t ws_size,
                              hipStream_t stream) {
    (void)in_sizes; (void)n_in; (void)out_size; (void)ws_size;
    const float* x  = (const float*)d_in[0];
    const int*   tg = (const int*)d_in[1];
    float* out = (float*)d_out;

    double* partials   = (double*)d_ws;                          // 2080 * 8B
    unsigned short* xb = (unsigned short*)((char*)d_ws + 32768); // 4MB bf16 X (frag-major)

    convert_k<<<1024, 256, 0, stream>>>(x, xb);
    gemm_loss_k<<<2080, 256, 0, stream>>>(xb, tg, partials);
    finalize_k<<<1, 256, 0, stream>>>(partials, out);
}